// Round 14
// baseline (290.887 us; speedup 1.0000x reference)
//
#include <hip/hip_runtime.h>
#include <math.h>

#define NN 100000
#define EE 1600000
#define GG 1000
#define NBUK 391                    // ceil(NN/256) buckets of 256 dst nodes
#define BCAP 4608                   // bucket capacity: mean 4092, +8 sigma
#define EPB 8192                    // edges per binning block (512 thr x 16)
#define NBINBLK ((EE + EPB - 1) / EPB)   // 196

__device__ __forceinline__ unsigned char f32_to_fp8(float a) {
    return (unsigned char)(__builtin_amdgcn_cvt_pk_fp8_f32(a, a, 0, false) & 0xFF);
}
__device__ __forceinline__ float fp8_to_f32(unsigned b) {
    return __builtin_amdgcn_cvt_f32_fp8((int)b, 0);
}

// ---- segment boundaries of sorted batch + bukcnt zeroing --------------------
__global__ void k_bound(const int* __restrict__ batch, int* __restrict__ bnd,
                        int* __restrict__ bukcnt, int n) {
    int i = blockIdx.x * blockDim.x + threadIdx.x;
    if (i < n) {
        int b = batch[i];
        if (i == 0 || batch[i - 1] != b) bnd[b] = i;
    }
    if (i == 0) bnd[GG] = n;
    if (i < NBUK) bukcnt[i] = 0;
}

// ---- pass 1: bin edges by dst>>8 into fixed-capacity bucket arrays ----------
// record: x = (local_dst<<24) | src (src < 2^17), y = float bits of weight
__global__ __launch_bounds__(512)
void k_bin(const int* __restrict__ src, const int* __restrict__ dst,
           const float* __restrict__ ew, int* __restrict__ bukcnt,
           uint2* __restrict__ ep1, int E) {
    __shared__ int hist[NBUK];
    __shared__ int gbase[NBUK];
    int tid = threadIdx.x;
    for (int i = tid; i < NBUK; i += 512) hist[i] = 0;
    __syncthreads();

    int base = blockIdx.x * EPB;
    int b[16], rank[16];
    unsigned x[16], w[16];
#pragma unroll
    for (int u = 0; u < 16; u++) {
        int e = base + u * 512 + tid;
        if (e < E) {
            int d = dst[e];
            b[u] = d >> 8;
            x[u] = ((unsigned)(d & 255) << 24) | (unsigned)src[e];
            w[u] = __float_as_uint(ew[e]);
            rank[u] = atomicAdd(&hist[b[u]], 1);
        } else b[u] = -1;
    }
    __syncthreads();
    for (int i = tid; i < NBUK; i += 512) {
        int h = hist[i];
        gbase[i] = h ? atomicAdd(&bukcnt[i], h) : 0;
    }
    __syncthreads();
#pragma unroll
    for (int u = 0; u < 16; u++) {
        if (b[u] >= 0) ep1[(size_t)b[u] * BCAP + gbase[b[u]] + rank[u]] = make_uint2(x[u], w[u]);
    }
}

// ---- exclusive scan of bucket counts -> bukbase; also counts[] --------------
__global__ void k_bukscan(const int* __restrict__ bukcnt, int* __restrict__ bukbase,
                          int* __restrict__ rowptr, const int* __restrict__ bnd,
                          float* __restrict__ counts) {
    __shared__ int s[512];
    int tid = threadIdx.x;
    int v = (tid < NBUK) ? bukcnt[tid] : 0;
    s[tid] = v;
    __syncthreads();
    for (int off = 1; off < 512; off <<= 1) {
        int t = (tid >= off) ? s[tid - off] : 0;
        __syncthreads();
        s[tid] += t;
        __syncthreads();
    }
    if (tid < NBUK) bukbase[tid] = s[tid] - v;   // exclusive
    if (tid == 0) { bukbase[NBUK] = EE; rowptr[NN] = EE; }
    for (int g = tid; g < GG; g += 512) counts[g] = (float)(bnd[g + 1] - bnd[g]);
}

// ---- pass 2: per-bucket LDS hist + scan -> rowptr; scatter to CSR -----------
__global__ __launch_bounds__(512)
void k_bin2(const uint2* __restrict__ ep1, const int* __restrict__ bukcnt,
            const int* __restrict__ bukbase, uint2* __restrict__ ep2,
            int* __restrict__ rowptr, int n) {
    __shared__ int h[256];
    __shared__ int s[256];
    __shared__ int cur[256];
    int tid = threadIdx.x;
    int bk = blockIdx.x;
    if (tid < 256) h[tid] = 0;
    __syncthreads();
    int cnt = bukcnt[bk];
    size_t ebase = (size_t)bk * BCAP;
    for (int e = tid; e < cnt; e += 512)
        atomicAdd(&h[ep1[ebase + e].x >> 24], 1);
    __syncthreads();
    if (tid < 256) s[tid] = h[tid];
    __syncthreads();
    for (int off = 1; off < 256; off <<= 1) {
        int t = 0;
        if (tid < 256 && tid >= off) t = s[tid - off];
        __syncthreads();
        if (tid < 256) s[tid] += t;
        __syncthreads();
    }
    if (tid < 256) {
        int base = bukbase[bk];
        int pfx = base + s[tid] - h[tid];
        int node = bk * 256 + tid;
        if (node < n) rowptr[node] = pfx;
        cur[tid] = pfx;
    }
    __syncthreads();
    for (int e = tid; e < cnt; e += 512) {
        uint2 r = ep1[ebase + e];
        int pos = atomicAdd(&cur[r.x >> 24], 1);
        ep2[pos] = r;
    }
}

// ---- 16-row GEMM tile: out[r][c] = fp8(sum_k in[r][k] * W[k][c]) -----------
// (layer 1 only; no activation). grid = NN/16; block = 256. Proven, no spills.
__global__ __launch_bounds__(256)
void k_gemm64(const float* __restrict__ in, const float* __restrict__ W,
              unsigned char* __restrict__ out) {
    __shared__ float Ws[64 * 64];
    __shared__ float Rs[16][64];
    int tid = threadIdx.x;
    const float4* W4 = (const float4*)W;
    float4* Ws4 = (float4*)Ws;
#pragma unroll
    for (int i = 0; i < 4; i++) Ws4[tid + 256 * i] = W4[tid + 256 * i];

    int row0 = blockIdx.x * 16;
    {
        const float4* in4 = (const float4*)(in + (size_t)row0 * 64);
        ((float4*)Rs)[tid] = in4[tid];
    }
    __syncthreads();

    int rgrp = tid >> 6;
    int c = tid & 63;
    float a0 = 0.f, a1 = 0.f, a2 = 0.f, a3 = 0.f;
#pragma unroll
    for (int k = 0; k < 64; k++) {
        float wv = Ws[k * 64 + c];
        a0 = fmaf(Rs[rgrp * 4 + 0][k], wv, a0);
        a1 = fmaf(Rs[rgrp * 4 + 1][k], wv, a1);
        a2 = fmaf(Rs[rgrp * 4 + 2][k], wv, a2);
        a3 = fmaf(Rs[rgrp * 4 + 3][k], wv, a3);
    }
    size_t ob = (size_t)(row0 + rgrp * 4) * 64 + c;
    out[ob      ] = f32_to_fp8(a0);
    out[ob + 64 ] = f32_to_fp8(a1);
    out[ob + 128] = f32_to_fp8(a2);
    out[ob + 192] = f32_to_fp8(a3);
}

// ---- gather1 + fused gemm2: t2[node] = fp8( sigmoid(acc/cp + b1) @ W2 ) -----
// One wave per node (8 waves/block). Gather loop identical to proven R9/R13.
// Epilogue uses idle issue slots: per-wave LDS row buffer + LDS-staged W2.
__global__ __launch_bounds__(512)
void k_gather_fg2(const unsigned char* __restrict__ t, const int* __restrict__ rowptr,
                  const uint2* __restrict__ ep, unsigned char* __restrict__ t2,
                  const float* __restrict__ W2, const float* __restrict__ b1,
                  const float* __restrict__ counts, const int* __restrict__ batch,
                  int n) {
    __shared__ float Ws[64 * 64];      // 16 KB: W2 staged
    __shared__ float rowbuf[8][64];    // 2 KB: per-wave row scratch
    int tid = threadIdx.x;
    const float4* W4 = (const float4*)W2;
    float4* Ws4 = (float4*)Ws;
#pragma unroll
    for (int i = 0; i < 2; i++) Ws4[tid + 512 * i] = W4[tid + 512 * i];
    __syncthreads();

    int wv = tid >> 6;                 // wave 0..7
    int lane = tid & 63;
    int wid = blockIdx.x * 8 + wv;     // grid = NN/8 exactly (NN % 8 == 0)
    wid = __builtin_amdgcn_readfirstlane(wid);
    if (wid >= n) return;
    int beg = rowptr[wid], end = rowptr[wid + 1];
    float acc = 0.f;
    int e = beg;
    for (; e + 8 <= end; e += 8) {
        uint2 r[8];
#pragma unroll
        for (int u = 0; u < 8; u++) r[u] = ep[e + u];
        float v[8];
#pragma unroll
        for (int u = 0; u < 8; u++)
            v[u] = fp8_to_f32(t[(size_t)(r[u].x & 0xFFFFFFu) * 64 + lane]);
#pragma unroll
        for (int u = 0; u < 8; u++) acc = fmaf(__uint_as_float(r[u].y), v[u], acc);
    }
    for (; e < end; e++) {
        uint2 r = ep[e];
        acc = fmaf(__uint_as_float(r.y),
                   fp8_to_f32(t[(size_t)(r.x & 0xFFFFFFu) * 64 + lane]), acc);
    }
    // epilogue: h = sigmoid(acc/cp + b1[lane]); u = h-row @ W2; t2 = fp8(u)
    float cp = counts[batch[wid]];
    float h = acc / cp + b1[lane];
    h = 1.f / (1.f + __expf(-h));
    rowbuf[wv][lane] = h;              // wave-local LDS; compiler orders via lgkmcnt
    float u = 0.f;
#pragma unroll
    for (int k = 0; k < 64; k++)
        u = fmaf(rowbuf[wv][k], Ws[k * 64 + lane], u);   // broadcast + stride-1: conflict-free
    t2[(size_t)wid * 64 + lane] = f32_to_fp8(u);
}

// ---- gather2 with fused sigmoid+dot(W3): y[node] ----------------------------
__global__ void k_gather64y(const unsigned char* __restrict__ t, const int* __restrict__ rowptr,
                            const uint2* __restrict__ ep, float* __restrict__ outp,
                            const float* __restrict__ b2, const float* __restrict__ W3,
                            const float* __restrict__ counts, const int* __restrict__ batch,
                            int n) {
    int wid = (blockIdx.x * blockDim.x + threadIdx.x) >> 6;
    int lane = threadIdx.x & 63;
    wid = __builtin_amdgcn_readfirstlane(wid);
    if (wid >= n) return;
    int beg = rowptr[wid], end = rowptr[wid + 1];
    float acc = 0.f;
    int e = beg;
    for (; e + 8 <= end; e += 8) {
        uint2 r[8];
#pragma unroll
        for (int u = 0; u < 8; u++) r[u] = ep[e + u];
        float v[8];
#pragma unroll
        for (int u = 0; u < 8; u++)
            v[u] = fp8_to_f32(t[(size_t)(r[u].x & 0xFFFFFFu) * 64 + lane]);
#pragma unroll
        for (int u = 0; u < 8; u++) acc = fmaf(__uint_as_float(r[u].y), v[u], acc);
    }
    for (; e < end; e++) {
        uint2 r = ep[e];
        acc = fmaf(__uint_as_float(r.y),
                   fp8_to_f32(t[(size_t)(r.x & 0xFFFFFFu) * 64 + lane]), acc);
    }
    float cp = counts[batch[wid]];
    float v = acc / cp + b2[lane];
    v = 1.f / (1.f + __expf(-v));
    v *= W3[lane];
#pragma unroll
    for (int off = 32; off > 0; off >>= 1) v += __shfl_down(v, off, 64);
    if (lane == 0) outp[wid] = v;
}

// ---- layer-3 per-node gather: y3[node] = sum_e w_e * y[src_e] ---------------
__global__ void k_y3(const float* __restrict__ y, const int* __restrict__ rowptr,
                     const uint2* __restrict__ ep, float* __restrict__ y3, int n) {
    int gtid = blockIdx.x * blockDim.x + threadIdx.x;
    int node = gtid >> 4;
    int ln = threadIdx.x & 15;
    if (node >= n) return;
    int beg = rowptr[node], end = rowptr[node + 1];
    float acc = 0.f;
    for (int e = beg + ln; e < end; e += 16) {
        uint2 r = ep[e];
        acc = fmaf(__uint_as_float(r.y), y[r.x & 0xFFFFFFu], acc);
    }
#pragma unroll
    for (int off = 1; off < 16; off <<= 1) acc += __shfl_xor(acc, off, 16);
    if (ln == 0) y3[node] = acc;
}

// ---- pool: out[g] = sum(y3 over segment)/c^2 + b3 ; one wave per graph ------
__global__ void k_pool(const float* __restrict__ y3, const int* __restrict__ bnd,
                       const float* __restrict__ b3, float* __restrict__ out) {
    int wid = (blockIdx.x * blockDim.x + threadIdx.x) >> 6;
    int lane = threadIdx.x & 63;
    if (wid >= GG) return;
    int beg = bnd[wid], end = bnd[wid + 1];
    float c = (float)(end - beg);
    float acc = 0.f;
    for (int i = beg + lane; i < end; i += 64) acc += y3[i];
#pragma unroll
    for (int off = 32; off > 0; off >>= 1) acc += __shfl_down(acc, off, 64);
    if (lane == 0) out[wid] = acc / (c * c) + b3[0];
}

extern "C" void kernel_launch(void* const* d_in, const int* in_sizes, int n_in,
                              void* d_out, int out_size, void* d_ws, size_t ws_size,
                              hipStream_t stream) {
    const float* x     = (const float*)d_in[0];
    const int*   ei    = (const int*)d_in[1];
    const int*   src   = ei;
    const int*   dst   = ei + EE;
    const float* ew    = (const float*)d_in[2];
    const int*   batch = (const int*)d_in[3];
    const float* W1    = (const float*)d_in[4];
    const float* b1    = (const float*)d_in[5];
    const float* W2    = (const float*)d_in[6];
    const float* b2    = (const float*)d_in[7];
    const float* W3    = (const float*)d_in[8];
    const float* b3    = (const float*)d_in[9];
    float* out = (float*)d_out;

    // workspace carve-up (no agg buffer anymore)
    unsigned char* t  = (unsigned char*)d_ws;          // N*64 fp8 (6.4 MB)  layer-1 table
    unsigned char* t2 = t + (size_t)NN * 64;           // N*64 fp8 (6.4 MB)  layer-2 table
    float* y      = (float*)(t2 + (size_t)NN * 64);    // N floats
    float* y3     = y + NN;                            // N floats
    float* counts = y3 + NN;                           // G floats
    uint2* ep2    = (uint2*)(counts + GG);             // E uint2 (final CSR records)
    int*   bukcnt = (int*)(ep2 + EE);                  // NBUK ints
    int*   bukbase= bukcnt + NBUK;                     // NBUK+1 ints
    int*   rowptr = bukbase + NBUK + 1;                // NN+1 ints
    int*   bnd    = rowptr + NN + 1;                   // GG+1 ints
    uint2* ep1    = (uint2*)(bnd + GG + 1);            // NBUK*BCAP uint2 (14.4 MB)

    // boundaries + bukcnt zero (fused); bucket-local CSR build
    k_bound<<<(NN + 255) / 256, 256, 0, stream>>>(batch, bnd, bukcnt, NN);
    k_bin<<<NBINBLK, 512, 0, stream>>>(src, dst, ew, bukcnt, ep1, EE);
    k_bukscan<<<1, 512, 0, stream>>>(bukcnt, bukbase, rowptr, bnd, counts);
    k_bin2<<<NBUK, 512, 0, stream>>>(ep1, bukcnt, bukbase, ep2, rowptr, NN);

    int gblk = (int)(((size_t)NN * 64 + 255) / 256);

    // layer 1: t = fp8(x @ W1)
    k_gemm64<<<NN / 16, 256, 0, stream>>>(x, W1, t);

    // gather1 + fused layer-2 transform: t2 = fp8(sigmoid(gather(t)/cp + b1) @ W2)
    k_gather_fg2<<<NN / 8, 512, 0, stream>>>(t, rowptr, ep2, t2, W2, b1, counts, batch, NN);

    // gather2 + fused sigmoid+dot(W3): y
    k_gather64y<<<gblk, 256, 0, stream>>>(t2, rowptr, ep2, y, b2, W3, counts, batch, NN);

    // layer 3: y3[node] ; pool: wave per graph (all atomic-free)
    k_y3<<<((size_t)NN * 16 + 255) / 256, 256, 0, stream>>>(y, rowptr, ep2, y3, NN);
    k_pool<<<((size_t)GG * 64 + 255) / 256, 256, 0, stream>>>(y3, bnd, b3, out);
}

// Round 15
// 278.216 us; speedup vs baseline: 1.0455x; 1.0455x over previous
//
#include <hip/hip_runtime.h>
#include <hip/hip_fp16.h>
#include <math.h>

#define NN 100000
#define EE 1600000
#define GG 1000
#define NBUK 391                    // ceil(NN/256) buckets of 256 dst nodes
#define BCAP 4608                   // bucket capacity: mean 4092, +8 sigma
#define EPB 8192                    // edges per binning block (512 thr x 16)
#define NBINBLK ((EE + EPB - 1) / EPB)   // 196

__device__ __forceinline__ unsigned char f32_to_fp8(float a) {
    return (unsigned char)(__builtin_amdgcn_cvt_pk_fp8_f32(a, a, 0, false) & 0xFF);
}
__device__ __forceinline__ float fp8_to_f32(unsigned b) {
    return __builtin_amdgcn_cvt_f32_fp8((int)b, 0);
}

// ---- segment boundaries of sorted batch + bukcnt zeroing --------------------
__global__ void k_bound(const int* __restrict__ batch, int* __restrict__ bnd,
                        int* __restrict__ bukcnt, int n) {
    int i = blockIdx.x * blockDim.x + threadIdx.x;
    if (i < n) {
        int b = batch[i];
        if (i == 0 || batch[i - 1] != b) bnd[b] = i;
    }
    if (i == 0) bnd[GG] = n;
    if (i < NBUK) bukcnt[i] = 0;
}

// ---- pass 1: bin edges by dst>>8 into fixed-capacity bucket arrays ----------
// ep1 record: x = (local_dst<<24) | src, y = float bits of weight
__global__ __launch_bounds__(512)
void k_bin(const int* __restrict__ src, const int* __restrict__ dst,
           const float* __restrict__ ew, int* __restrict__ bukcnt,
           uint2* __restrict__ ep1, int E) {
    __shared__ int hist[NBUK];
    __shared__ int gbase[NBUK];
    int tid = threadIdx.x;
    for (int i = tid; i < NBUK; i += 512) hist[i] = 0;
    __syncthreads();

    int base = blockIdx.x * EPB;
    int b[16], rank[16];
    unsigned x[16], w[16];
#pragma unroll
    for (int u = 0; u < 16; u++) {
        int e = base + u * 512 + tid;
        if (e < E) {
            int d = dst[e];
            b[u] = d >> 8;
            x[u] = ((unsigned)(d & 255) << 24) | (unsigned)src[e];
            w[u] = __float_as_uint(ew[e]);
            rank[u] = atomicAdd(&hist[b[u]], 1);
        } else b[u] = -1;
    }
    __syncthreads();
    for (int i = tid; i < NBUK; i += 512) {
        int h = hist[i];
        gbase[i] = h ? atomicAdd(&bukcnt[i], h) : 0;
    }
    __syncthreads();
#pragma unroll
    for (int u = 0; u < 16; u++) {
        if (b[u] >= 0) ep1[(size_t)b[u] * BCAP + gbase[b[u]] + rank[u]] = make_uint2(x[u], w[u]);
    }
}

// ---- exclusive scan of bucket counts -> bukbase; also counts[] --------------
__global__ void k_bukscan(const int* __restrict__ bukcnt, int* __restrict__ bukbase,
                          int* __restrict__ rowptr, const int* __restrict__ bnd,
                          float* __restrict__ counts) {
    __shared__ int s[512];
    int tid = threadIdx.x;
    int v = (tid < NBUK) ? bukcnt[tid] : 0;
    s[tid] = v;
    __syncthreads();
    for (int off = 1; off < 512; off <<= 1) {
        int t = (tid >= off) ? s[tid - off] : 0;
        __syncthreads();
        s[tid] += t;
        __syncthreads();
    }
    if (tid < NBUK) bukbase[tid] = s[tid] - v;   // exclusive
    if (tid == 0) { bukbase[NBUK] = EE; rowptr[NN] = EE; }
    for (int g = tid; g < GG; g += 512) counts[g] = (float)(bnd[g + 1] - bnd[g]);
}

// ---- pass 2: per-bucket LDS hist + scan -> rowptr; scatter packed 4B CSR ----
// ep2 record: (w15 << 17) | src   (w15 = round(w * 32768), src < 2^17)
__global__ __launch_bounds__(512)
void k_bin2(const uint2* __restrict__ ep1, const int* __restrict__ bukcnt,
            const int* __restrict__ bukbase, unsigned* __restrict__ ep2,
            int* __restrict__ rowptr, int n) {
    __shared__ int h[256];
    __shared__ int s[256];
    __shared__ int cur[256];
    int tid = threadIdx.x;
    int bk = blockIdx.x;
    if (tid < 256) h[tid] = 0;
    __syncthreads();
    int cnt = bukcnt[bk];
    size_t ebase = (size_t)bk * BCAP;
    for (int e = tid; e < cnt; e += 512)
        atomicAdd(&h[ep1[ebase + e].x >> 24], 1);
    __syncthreads();
    if (tid < 256) s[tid] = h[tid];
    __syncthreads();
    for (int off = 1; off < 256; off <<= 1) {
        int t = 0;
        if (tid < 256 && tid >= off) t = s[tid - off];
        __syncthreads();
        if (tid < 256) s[tid] += t;
        __syncthreads();
    }
    if (tid < 256) {
        int base = bukbase[bk];
        int pfx = base + s[tid] - h[tid];
        int node = bk * 256 + tid;
        if (node < n) rowptr[node] = pfx;
        cur[tid] = pfx;
    }
    __syncthreads();
    for (int e = tid; e < cnt; e += 512) {
        uint2 r = ep1[ebase + e];
        int pos = atomicAdd(&cur[r.x >> 24], 1);
        unsigned wq = (unsigned)fminf(__uint_as_float(r.y) * 32768.f + 0.5f, 32767.f);
        ep2[pos] = (wq << 17) | (r.x & 0x1FFFFu);
    }
}

// ---- 16-row GEMM tile: out = fp8(in @ W), in fp32 or fp16, no activation ----
// grid = NN/16 exactly; block = 256. Proven shape (R9-R13), no spills.
template<bool HALF_IN>
__global__ __launch_bounds__(256)
void k_gemm64(const void* __restrict__ inp, const float* __restrict__ W,
              unsigned char* __restrict__ out) {
    __shared__ float Ws[64 * 64];
    __shared__ float Rs[16][64];
    int tid = threadIdx.x;
    const float4* W4 = (const float4*)W;
    float4* Ws4 = (float4*)Ws;
#pragma unroll
    for (int i = 0; i < 4; i++) Ws4[tid + 256 * i] = W4[tid + 256 * i];

    int row0 = blockIdx.x * 16;
    if (HALF_IN) {
        const ushort4* in4 = (const ushort4*)((const __half*)inp + (size_t)row0 * 64);
        ushort4 q = in4[tid];            // 4 halves = elements tid*4..tid*4+3
        float4 v;
        v.x = __half2float(__ushort_as_half(q.x));
        v.y = __half2float(__ushort_as_half(q.y));
        v.z = __half2float(__ushort_as_half(q.z));
        v.w = __half2float(__ushort_as_half(q.w));
        ((float4*)Rs)[tid] = v;
    } else {
        const float4* in4 = (const float4*)((const float*)inp + (size_t)row0 * 64);
        ((float4*)Rs)[tid] = in4[tid];
    }
    __syncthreads();

    int rgrp = tid >> 6;
    int c = tid & 63;
    float a0 = 0.f, a1 = 0.f, a2 = 0.f, a3 = 0.f;
#pragma unroll
    for (int k = 0; k < 64; k++) {
        float wv = Ws[k * 64 + c];
        a0 = fmaf(Rs[rgrp * 4 + 0][k], wv, a0);
        a1 = fmaf(Rs[rgrp * 4 + 1][k], wv, a1);
        a2 = fmaf(Rs[rgrp * 4 + 2][k], wv, a2);
        a3 = fmaf(Rs[rgrp * 4 + 3][k], wv, a3);
    }
    size_t ob = (size_t)(row0 + rgrp * 4) * 64 + c;
    out[ob      ] = f32_to_fp8(a0);
    out[ob + 64 ] = f32_to_fp8(a1);
    out[ob + 128] = f32_to_fp8(a2);
    out[ob + 192] = f32_to_fp8(a3);
}

// ---- wave-per-node CSR gather, packed 4B records, lane-local epilogues ------
// MODE 0 (H): hh[node][lane] = fp16( sigmoid(acc/cp + bv[lane]) )
// MODE 1 (Y): y[node] = sum_lane sigmoid(acc/cp + bv[lane]) * W3[lane]
template<int MODE>
__global__ void k_gather64(const unsigned char* __restrict__ t, const int* __restrict__ rowptr,
                           const unsigned* __restrict__ ep, void* __restrict__ outp,
                           const float* __restrict__ bv, const float* __restrict__ W3,
                           const float* __restrict__ counts, const int* __restrict__ batch,
                           int n) {
    int wid = (blockIdx.x * blockDim.x + threadIdx.x) >> 6;
    int lane = threadIdx.x & 63;
    wid = __builtin_amdgcn_readfirstlane(wid);   // wave-uniform -> scalar edge loads
    if (wid >= n) return;
    int beg = rowptr[wid], end = rowptr[wid + 1];
    float acc = 0.f;
    int e = beg;
    for (; e + 8 <= end; e += 8) {
        unsigned r[8];
#pragma unroll
        for (int u = 0; u < 8; u++) r[u] = ep[e + u];
        float v[8];
#pragma unroll
        for (int u = 0; u < 8; u++)
            v[u] = fp8_to_f32(t[(size_t)(r[u] & 0x1FFFFu) * 64 + lane]);
#pragma unroll
        for (int u = 0; u < 8; u++)
            acc = fmaf((float)(r[u] >> 17) * 0x1p-15f, v[u], acc);
    }
    for (; e < end; e++) {
        unsigned r = ep[e];
        acc = fmaf((float)(r >> 17) * 0x1p-15f,
                   fp8_to_f32(t[(size_t)(r & 0x1FFFFu) * 64 + lane]), acc);
    }
    float cp = counts[batch[wid]];
    float v = acc / cp + bv[lane];
    v = 1.f / (1.f + __expf(-v));
    if (MODE == 0) {
        ((__half*)outp)[(size_t)wid * 64 + lane] = __float2half(v);
    } else {
        v *= W3[lane];
#pragma unroll
        for (int off = 32; off > 0; off >>= 1) v += __shfl_down(v, off, 64);
        if (lane == 0) ((float*)outp)[wid] = v;
    }
}

// ---- layer-3 per-node gather: y3[node] = sum_e w_e * y[src_e] ---------------
__global__ void k_y3(const float* __restrict__ y, const int* __restrict__ rowptr,
                     const unsigned* __restrict__ ep, float* __restrict__ y3, int n) {
    int gtid = blockIdx.x * blockDim.x + threadIdx.x;
    int node = gtid >> 4;
    int ln = threadIdx.x & 15;
    if (node >= n) return;
    int beg = rowptr[node], end = rowptr[node + 1];
    float acc = 0.f;
    for (int e = beg + ln; e < end; e += 16) {
        unsigned r = ep[e];
        acc = fmaf((float)(r >> 17) * 0x1p-15f, y[r & 0x1FFFFu], acc);
    }
#pragma unroll
    for (int off = 1; off < 16; off <<= 1) acc += __shfl_xor(acc, off, 16);
    if (ln == 0) y3[node] = acc;
}

// ---- pool: out[g] = sum(y3 over segment)/c^2 + b3 ; one wave per graph ------
__global__ void k_pool(const float* __restrict__ y3, const int* __restrict__ bnd,
                       const float* __restrict__ b3, float* __restrict__ out) {
    int wid = (blockIdx.x * blockDim.x + threadIdx.x) >> 6;
    int lane = threadIdx.x & 63;
    if (wid >= GG) return;
    int beg = bnd[wid], end = bnd[wid + 1];
    float c = (float)(end - beg);
    float acc = 0.f;
    for (int i = beg + lane; i < end; i += 64) acc += y3[i];
#pragma unroll
    for (int off = 32; off > 0; off >>= 1) acc += __shfl_down(acc, off, 64);
    if (lane == 0) out[wid] = acc / (c * c) + b3[0];
}

extern "C" void kernel_launch(void* const* d_in, const int* in_sizes, int n_in,
                              void* d_out, int out_size, void* d_ws, size_t ws_size,
                              hipStream_t stream) {
    const float* x     = (const float*)d_in[0];
    const int*   ei    = (const int*)d_in[1];
    const int*   src   = ei;
    const int*   dst   = ei + EE;
    const float* ew    = (const float*)d_in[2];
    const int*   batch = (const int*)d_in[3];
    const float* W1    = (const float*)d_in[4];
    const float* b1    = (const float*)d_in[5];
    const float* W2    = (const float*)d_in[6];
    const float* b2    = (const float*)d_in[7];
    const float* W3    = (const float*)d_in[8];
    const float* b3    = (const float*)d_in[9];
    float* out = (float*)d_out;

    // workspace carve-up
    unsigned char* t  = (unsigned char*)d_ws;          // N*64 fp8 (6.4 MB)  layer-1 table
    unsigned char* t2 = t + (size_t)NN * 64;           // N*64 fp8 (6.4 MB)  layer-2 table
    __half* hh    = (__half*)(t2 + (size_t)NN * 64);   // N*64 fp16 (12.8 MB) activated h
    float* y      = (float*)(hh + (size_t)NN * 64);    // N floats
    float* y3     = y + NN;                            // N floats
    float* counts = y3 + NN;                           // G floats
    unsigned* ep2 = (unsigned*)(counts + GG);          // E uint (packed CSR, 6.4 MB)
    int*   bukcnt = (int*)(ep2 + EE);                  // NBUK ints
    int*   bukbase= bukcnt + NBUK;                     // NBUK+1 ints
    int*   rowptr = bukbase + NBUK + 1;                // NN+1 ints
    int*   bnd    = rowptr + NN + 1;                   // GG+1 ints
    uint2* ep1    = (uint2*)(bnd + GG + 1);            // NBUK*BCAP uint2 (14.4 MB)

    // boundaries + bukcnt zero (fused); bucket-local CSR build
    k_bound<<<(NN + 255) / 256, 256, 0, stream>>>(batch, bnd, bukcnt, NN);
    k_bin<<<NBINBLK, 512, 0, stream>>>(src, dst, ew, bukcnt, ep1, EE);
    k_bukscan<<<1, 512, 0, stream>>>(bukcnt, bukbase, rowptr, bnd, counts);
    k_bin2<<<NBUK, 512, 0, stream>>>(ep1, bukcnt, bukbase, ep2, rowptr, NN);

    int gblk = (int)(((size_t)NN * 64 + 255) / 256);

    // layer 1: t = fp8(x @ W1)
    k_gemm64<false><<<NN / 16, 256, 0, stream>>>(x, W1, t);

    // gather1 (+ lane-local sigmoid): hh = fp16(sigmoid(gather(t)/cp + b1))
    k_gather64<0><<<gblk, 256, 0, stream>>>(t, rowptr, ep2, hh, b1, nullptr, counts, batch, NN);

    // layer 2: t2 = fp8(hh @ W2)
    k_gemm64<true><<<NN / 16, 256, 0, stream>>>(hh, W2, t2);

    // gather2 (+ fused sigmoid + dot W3): y
    k_gather64<1><<<gblk, 256, 0, stream>>>(t2, rowptr, ep2, y, b2, W3, counts, batch, NN);

    // layer 3: y3[node] ; pool: wave per graph (all atomic-free)
    k_y3<<<((size_t)NN * 16 + 255) / 256, 256, 0, stream>>>(y, rowptr, ep2, y3, NN);
    k_pool<<<((size_t)GG * 64 + 255) / 256, 256, 0, stream>>>(y3, bnd, b3, out);
}

// Round 16
// 267.393 us; speedup vs baseline: 1.0879x; 1.0405x over previous
//
#include <hip/hip_runtime.h>
#include <hip/hip_fp16.h>
#include <math.h>

#define NN 100000
#define EE 1600000
#define GG 1000
#define NBUK 391                    // ceil(NN/256) buckets of 256 dst nodes
#define BCAP 4608                   // bucket capacity: mean 4092, +8 sigma
#define EPB 8192                    // edges per binning block (512 thr x 16)
#define NBINBLK ((EE + EPB - 1) / EPB)   // 196
#define NBNDBLK ((NN + 511) / 512)       // 196 (bound blocks, 512 thr)
#define GEMM1BLK (NN / 32)               // 3125 (32 rows per 512-thr block)

__device__ __forceinline__ unsigned char f32_to_fp8(float a) {
    return (unsigned char)(__builtin_amdgcn_cvt_pk_fp8_f32(a, a, 0, false) & 0xFF);
}
__device__ __forceinline__ float fp8_to_f32(unsigned b) {
    return __builtin_amdgcn_cvt_f32_fp8((int)b, 0);
}

// ==== U1: blocks [0,NBINBLK) = edge binning ; [NBINBLK, +NBNDBLK) = bounds ===
// bukcnt must be zeroed BEFORE this dispatch (memset) — bin/bound order is undefined.
__global__ __launch_bounds__(512)
void k_binbound(const int* __restrict__ src, const int* __restrict__ dst,
                const float* __restrict__ ew, int* __restrict__ bukcnt,
                uint2* __restrict__ ep1,
                const int* __restrict__ batch, int* __restrict__ bnd, int E) {
    __shared__ int hist[NBUK];
    __shared__ int gbase[NBUK];
    int tid = threadIdx.x;
    if (blockIdx.x < NBINBLK) {
        for (int i = tid; i < NBUK; i += 512) hist[i] = 0;
        __syncthreads();
        int base = blockIdx.x * EPB;
        int b[16], rank[16];
        unsigned x[16], w[16];
#pragma unroll
        for (int u = 0; u < 16; u++) {
            int e = base + u * 512 + tid;
            if (e < E) {
                int d = dst[e];
                b[u] = d >> 8;
                x[u] = ((unsigned)(d & 255) << 24) | (unsigned)src[e];
                w[u] = __float_as_uint(ew[e]);
                rank[u] = atomicAdd(&hist[b[u]], 1);
            } else b[u] = -1;
        }
        __syncthreads();
        for (int i = tid; i < NBUK; i += 512) {
            int h = hist[i];
            gbase[i] = h ? atomicAdd(&bukcnt[i], h) : 0;
        }
        __syncthreads();
#pragma unroll
        for (int u = 0; u < 16; u++) {
            if (b[u] >= 0) ep1[(size_t)b[u] * BCAP + gbase[b[u]] + rank[u]] = make_uint2(x[u], w[u]);
        }
    } else {
        int i = (blockIdx.x - NBINBLK) * 512 + tid;
        if (i < NN) {
            int b = batch[i];
            if (i == 0 || batch[i - 1] != b) bnd[b] = i;
        }
        if (i == 0) bnd[GG] = NN;
    }
}

// ---- exclusive scan of bucket counts -> bukbase; also counts[] --------------
__global__ void k_bukscan(const int* __restrict__ bukcnt, int* __restrict__ bukbase,
                          int* __restrict__ rowptr, const int* __restrict__ bnd,
                          float* __restrict__ counts) {
    __shared__ int s[512];
    int tid = threadIdx.x;
    int v = (tid < NBUK) ? bukcnt[tid] : 0;
    s[tid] = v;
    __syncthreads();
    for (int off = 1; off < 512; off <<= 1) {
        int t = (tid >= off) ? s[tid - off] : 0;
        __syncthreads();
        s[tid] += t;
        __syncthreads();
    }
    if (tid < NBUK) bukbase[tid] = s[tid] - v;   // exclusive
    if (tid == 0) { bukbase[NBUK] = EE; rowptr[NN] = EE; }
    for (int g = tid; g < GG; g += 512) counts[g] = (float)(bnd[g + 1] - bnd[g]);
}

// ==== U2: blocks [0,NBUK) = bin2 (LDS-staged) ; [NBUK, +GEMM1BLK) = gemm1 ====
// LDS union: bin2 = 36864 (stage) + 3*1024 = 39936 B ; gemm1 = 16384 + 8192 B.
__global__ __launch_bounds__(512)
void k_bin2gemm1(const uint2* __restrict__ ep1, const int* __restrict__ bukcnt,
                 const int* __restrict__ bukbase, unsigned* __restrict__ ep2,
                 int* __restrict__ rowptr,
                 const float* __restrict__ x, const float* __restrict__ W1,
                 unsigned char* __restrict__ t, int n) {
    __shared__ __align__(16) unsigned char smem[39936];
    int tid = threadIdx.x;
    int bk = blockIdx.x;
    if (bk < NBUK) {
        uint2* stage = (uint2*)smem;                 // 36864 B
        int* h   = (int*)(smem + 36864);             // 1024 B
        int* s   = h + 256;                          // 1024 B
        int* cur = s + 256;                          // 1024 B
        if (tid < 256) h[tid] = 0;
        __syncthreads();
        int cnt = bukcnt[bk];
        size_t ebase = (size_t)bk * BCAP;
        for (int e = tid; e < cnt; e += 512) {
            uint2 r = ep1[ebase + e];
            stage[e] = r;
            atomicAdd(&h[r.x >> 24], 1);
        }
        __syncthreads();
        if (tid < 256) s[tid] = h[tid];
        __syncthreads();
        for (int off = 1; off < 256; off <<= 1) {
            int tv = 0;
            if (tid < 256 && tid >= off) tv = s[tid - off];
            __syncthreads();
            if (tid < 256) s[tid] += tv;
            __syncthreads();
        }
        if (tid < 256) {
            int base = bukbase[bk];
            int pfx = base + s[tid] - h[tid];
            int node = bk * 256 + tid;
            if (node < n) rowptr[node] = pfx;
            cur[tid] = pfx;
        }
        __syncthreads();
        for (int e = tid; e < cnt; e += 512) {
            uint2 r = stage[e];
            int pos = atomicAdd(&cur[r.x >> 24], 1);
            unsigned wq = (unsigned)fminf(__uint_as_float(r.y) * 32768.f + 0.5f, 32767.f);
            ep2[pos] = (wq << 17) | (r.x & 0x1FFFFu);
        }
    } else {
        // gemm1: t = fp8(x @ W1), 32 rows/block, 4 rows/wave (proven register shape)
        float* Ws = (float*)smem;                    // 16384 B
        float (*Rs)[64] = (float (*)[64])(smem + 16384);   // 8192 B
        const float4* W4 = (const float4*)W1;
        float4* Ws4 = (float4*)Ws;
        Ws4[tid] = W4[tid];
        Ws4[tid + 512] = W4[tid + 512];
        int row0 = (bk - NBUK) * 32;
        const float4* in4 = (const float4*)(x + (size_t)row0 * 64);
        ((float4*)Rs)[tid] = in4[tid];
        __syncthreads();
        int rgrp = tid >> 6;                         // 0..7 -> rows rgrp*4..+3
        int c = tid & 63;
        float a0 = 0.f, a1 = 0.f, a2 = 0.f, a3 = 0.f;
#pragma unroll
        for (int k = 0; k < 64; k++) {
            float wv = Ws[k * 64 + c];
            a0 = fmaf(Rs[rgrp * 4 + 0][k], wv, a0);
            a1 = fmaf(Rs[rgrp * 4 + 1][k], wv, a1);
            a2 = fmaf(Rs[rgrp * 4 + 2][k], wv, a2);
            a3 = fmaf(Rs[rgrp * 4 + 3][k], wv, a3);
        }
        size_t ob = (size_t)(row0 + rgrp * 4) * 64 + c;
        t[ob      ] = f32_to_fp8(a0);
        t[ob + 64 ] = f32_to_fp8(a1);
        t[ob + 128] = f32_to_fp8(a2);
        t[ob + 192] = f32_to_fp8(a3);
    }
}

// ---- 16-row GEMM tile: t2 = fp8(hh @ W2), hh fp16 (proven, no spills) -------
__global__ __launch_bounds__(256)
void k_gemm64h(const __half* __restrict__ inp, const float* __restrict__ W,
               unsigned char* __restrict__ out) {
    __shared__ float Ws[64 * 64];
    __shared__ float Rs[16][64];
    int tid = threadIdx.x;
    const float4* W4 = (const float4*)W;
    float4* Ws4 = (float4*)Ws;
#pragma unroll
    for (int i = 0; i < 4; i++) Ws4[tid + 256 * i] = W4[tid + 256 * i];

    int row0 = blockIdx.x * 16;
    {
        const ushort4* in4 = (const ushort4*)(inp + (size_t)row0 * 64);
        ushort4 q = in4[tid];
        float4 v;
        v.x = __half2float(__ushort_as_half(q.x));
        v.y = __half2float(__ushort_as_half(q.y));
        v.z = __half2float(__ushort_as_half(q.z));
        v.w = __half2float(__ushort_as_half(q.w));
        ((float4*)Rs)[tid] = v;
    }
    __syncthreads();

    int rgrp = tid >> 6;
    int c = tid & 63;
    float a0 = 0.f, a1 = 0.f, a2 = 0.f, a3 = 0.f;
#pragma unroll
    for (int k = 0; k < 64; k++) {
        float wv = Ws[k * 64 + c];
        a0 = fmaf(Rs[rgrp * 4 + 0][k], wv, a0);
        a1 = fmaf(Rs[rgrp * 4 + 1][k], wv, a1);
        a2 = fmaf(Rs[rgrp * 4 + 2][k], wv, a2);
        a3 = fmaf(Rs[rgrp * 4 + 3][k], wv, a3);
    }
    size_t ob = (size_t)(row0 + rgrp * 4) * 64 + c;
    out[ob      ] = f32_to_fp8(a0);
    out[ob + 64 ] = f32_to_fp8(a1);
    out[ob + 128] = f32_to_fp8(a2);
    out[ob + 192] = f32_to_fp8(a3);
}

// ---- wave-per-node CSR gather, packed 4B records, lane-local epilogues ------
// MODE 0 (H): hh[node][lane] = fp16( sigmoid(acc/cp + bv[lane]) )
// MODE 1 (Y): y[node] = sum_lane sigmoid(acc/cp + bv[lane]) * W3[lane]
template<int MODE>
__global__ void k_gather64(const unsigned char* __restrict__ t, const int* __restrict__ rowptr,
                           const unsigned* __restrict__ ep, void* __restrict__ outp,
                           const float* __restrict__ bv, const float* __restrict__ W3,
                           const float* __restrict__ counts, const int* __restrict__ batch,
                           int n) {
    int wid = (blockIdx.x * blockDim.x + threadIdx.x) >> 6;
    int lane = threadIdx.x & 63;
    wid = __builtin_amdgcn_readfirstlane(wid);   // wave-uniform -> scalar edge loads
    if (wid >= n) return;
    int beg = rowptr[wid], end = rowptr[wid + 1];
    float acc = 0.f;
    int e = beg;
    for (; e + 8 <= end; e += 8) {
        unsigned r[8];
#pragma unroll
        for (int u = 0; u < 8; u++) r[u] = ep[e + u];
        float v[8];
#pragma unroll
        for (int u = 0; u < 8; u++)
            v[u] = fp8_to_f32(t[(size_t)(r[u] & 0x1FFFFu) * 64 + lane]);
#pragma unroll
        for (int u = 0; u < 8; u++)
            acc = fmaf((float)(r[u] >> 17) * 0x1p-15f, v[u], acc);
    }
    for (; e < end; e++) {
        unsigned r = ep[e];
        acc = fmaf((float)(r >> 17) * 0x1p-15f,
                   fp8_to_f32(t[(size_t)(r & 0x1FFFFu) * 64 + lane]), acc);
    }
    float cp = counts[batch[wid]];
    float v = acc / cp + bv[lane];
    v = 1.f / (1.f + __expf(-v));
    if (MODE == 0) {
        ((__half*)outp)[(size_t)wid * 64 + lane] = __float2half(v);
    } else {
        v *= W3[lane];
#pragma unroll
        for (int off = 32; off > 0; off >>= 1) v += __shfl_down(v, off, 64);
        if (lane == 0) ((float*)outp)[wid] = v;
    }
}

// ---- fused layer-3 gather + pool: one block per graph -----------------------
// out[g] = ( sum_{node in g} sum_e w_e*y[src_e] ) / c^2 + b3
__global__ __launch_bounds__(256)
void k_y3pool(const float* __restrict__ y, const int* __restrict__ rowptr,
              const unsigned* __restrict__ ep, const int* __restrict__ bnd,
              const float* __restrict__ b3, float* __restrict__ out) {
    __shared__ float red[256];
    int g = blockIdx.x;
    int tid = threadIdx.x;
    int nbeg = bnd[g], nend = bnd[g + 1];
    int ln = tid & 15;
    float tot = 0.f;
    for (int nd = nbeg + (tid >> 4); nd < nend; nd += 16) {
        int beg = rowptr[nd], end = rowptr[nd + 1];
        float acc = 0.f;
        for (int e = beg + ln; e < end; e += 16) {
            unsigned r = ep[e];
            acc = fmaf((float)(r >> 17) * 0x1p-15f, y[r & 0x1FFFFu], acc);
        }
#pragma unroll
        for (int off = 1; off < 16; off <<= 1) acc += __shfl_xor(acc, off, 16);
        if (ln == 0) tot += acc;
    }
    red[tid] = tot;
    __syncthreads();
    for (int off = 128; off > 0; off >>= 1) {
        if (tid < off) red[tid] += red[tid + off];
        __syncthreads();
    }
    if (tid == 0) {
        float c = (float)(nend - nbeg);
        out[g] = red[0] / (c * c) + b3[0];
    }
}

extern "C" void kernel_launch(void* const* d_in, const int* in_sizes, int n_in,
                              void* d_out, int out_size, void* d_ws, size_t ws_size,
                              hipStream_t stream) {
    const float* x     = (const float*)d_in[0];
    const int*   ei    = (const int*)d_in[1];
    const int*   src   = ei;
    const int*   dst   = ei + EE;
    const float* ew    = (const float*)d_in[2];
    const int*   batch = (const int*)d_in[3];
    const float* W1    = (const float*)d_in[4];
    const float* b1    = (const float*)d_in[5];
    const float* W2    = (const float*)d_in[6];
    const float* b2    = (const float*)d_in[7];
    const float* W3    = (const float*)d_in[8];
    const float* b3    = (const float*)d_in[9];
    float* out = (float*)d_out;

    // workspace carve-up
    unsigned char* t  = (unsigned char*)d_ws;          // N*64 fp8 (6.4 MB)  layer-1 table
    unsigned char* t2 = t + (size_t)NN * 64;           // N*64 fp8 (6.4 MB)  layer-2 table
    __half* hh    = (__half*)(t2 + (size_t)NN * 64);   // N*64 fp16 (12.8 MB) activated h
    float* y      = (float*)(hh + (size_t)NN * 64);    // N floats
    float* counts = y + NN;                            // G floats
    unsigned* ep2 = (unsigned*)(counts + GG);          // E uint (packed CSR, 6.4 MB)
    int*   bukcnt = (int*)(ep2 + EE);                  // NBUK ints
    int*   bukbase= bukcnt + NBUK;                     // NBUK+1 ints
    int*   rowptr = bukbase + NBUK + 1;                // NN+1 ints
    int*   bnd    = rowptr + NN + 1;                   // GG+1 ints
    int*   pad    = bnd + GG + 1;                      // 1 int (8B-align ep1)
    uint2* ep1    = (uint2*)(pad + 1);                 // NBUK*BCAP uint2 (14.4 MB)

    // zero bucket counters (must precede the merged bin/bound dispatch)
    hipMemsetAsync(bukcnt, 0, NBUK * sizeof(int), stream);

    // U1: edge binning || segment boundaries
    k_binbound<<<NBINBLK + NBNDBLK, 512, 0, stream>>>(src, dst, ew, bukcnt, ep1, batch, bnd, EE);
    k_bukscan<<<1, 512, 0, stream>>>(bukcnt, bukbase, rowptr, bnd, counts);

    // U2: bucket-local CSR finalize || layer-1 GEMM (independent, overlapped)
    k_bin2gemm1<<<NBUK + GEMM1BLK, 512, 0, stream>>>(ep1, bukcnt, bukbase, ep2, rowptr,
                                                     x, W1, t, NN);

    int gblk = (int)(((size_t)NN * 64 + 255) / 256);

    // gather1 (+ lane-local sigmoid): hh = fp16(sigmoid(gather(t)/cp + b1))
    k_gather64<0><<<gblk, 256, 0, stream>>>(t, rowptr, ep2, hh, b1, nullptr, counts, batch, NN);

    // layer 2: t2 = fp8(hh @ W2)
    k_gemm64h<<<NN / 16, 256, 0, stream>>>(hh, W2, t2);

    // gather2 (+ fused sigmoid + dot W3): y
    k_gather64<1><<<gblk, 256, 0, stream>>>(t2, rowptr, ep2, y, b2, W3, counts, batch, NN);

    // fused layer-3 gather + graph-mean pool (atomic-free)
    k_y3pool<<<GG, 256, 0, stream>>>(y, rowptr, ep2, bnd, b3, out);
}